// Round 9
// baseline (385.934 us; speedup 1.0000x reference)
//
#include <hip/hip_runtime.h>
#include <stdint.h>

typedef unsigned short u16;
typedef __attribute__((ext_vector_type(8))) short s16x8;   // 8 bf16 (4 VGPRs)
typedef __attribute__((ext_vector_type(8))) u16  u16x8;
typedef __attribute__((ext_vector_type(4))) u16  u16x4;
typedef __attribute__((ext_vector_type(4))) float f32x4;

#define T_TOKENS 2048
#define DM 1024
#define DH 4096
#define NE 8
#define BK 64
// 256-padded slot space
#define PAD2 256
#define MAXS2 (T_TOKENS*2 + NE*PAD2)    // 6144
#define RB1 (MAXS2/256)                 // 24  (ffn1 256-row blocks)
#define RB2 (MAXS2/128)                 // 48  (ffn2 128-row blocks)
// f32 fallback path: 128-padded
#define BM 128
#define BN 128
#define MAXSLOTS (T_TOKENS*2 + NE*BM)   // 5120
#define ROWBLK (MAXSLOTS/BM)            // 40

__device__ __forceinline__ u16 f2bf(float f) {
    union { float ff; uint32_t u; } v; v.ff = f;
    uint32_t r = v.u + 0x7fffu + ((v.u >> 16) & 1u);   // RNE
    return (u16)(r >> 16);
}

#define GLOAD_LDS16(gsrc, ldst) \
    __builtin_amdgcn_global_load_lds((const __attribute__((address_space(1))) uint32_t*)(gsrc), \
                                     (__attribute__((address_space(3))) uint32_t*)(ldst), 16, 0, 0)

// counted waits: N = loads-per-stage x (tiles in flight beyond current)
#define WAIT_VM6() asm volatile("s_waitcnt vmcnt(6)" ::: "memory")
#define WAIT_VM4() asm volatile("s_waitcnt vmcnt(4)" ::: "memory")
#define WAIT_VM0() asm volatile("s_waitcnt vmcnt(0)" ::: "memory")

// ---------- K0: convert x f32 -> bf16, zero control ints ----------
__global__ void k_convert(const float* __restrict__ x, u16* __restrict__ xbf,
                          int* __restrict__ ctrl) {
    int i = blockIdx.x * blockDim.x + threadIdx.x;
    const f32x4* xv = (const f32x4*)x;
    f32x4 a = xv[2*i], b = xv[2*i+1];
    u16x8 o;
    o[0]=f2bf(a[0]); o[1]=f2bf(a[1]); o[2]=f2bf(a[2]); o[3]=f2bf(a[3]);
    o[4]=f2bf(b[0]); o[5]=f2bf(b[1]); o[6]=f2bf(b[2]); o[7]=f2bf(b[3]);
    ((u16x8*)xbf)[i] = o;
    if (blockIdx.x == 0 && threadIdx.x < 32) ctrl[threadIdx.x] = 0;
}

// ---------- K0b: windowed transpose + f32->bf16  dst[e][(n-nw0)][k] = src[e][k][n] ----------
__global__ void __launch_bounds__(256) k_transpose(const float* __restrict__ src,
                                                   u16* __restrict__ dst,
                                                   int K, int N, int nw0, int NW) {
    __shared__ float tile[64][65];
    const int e = blockIdx.z;
    const int n0 = nw0 + blockIdx.x * 64, k0 = blockIdx.y * 64;
    const float* s = src + (size_t)e * K * N;
    u16* d = dst + (size_t)e * K * NW;
    const int tx = threadIdx.x & 15, ty = threadIdx.x >> 4;
    #pragma unroll
    for (int j = 0; j < 4; ++j) {
        int r = ty * 4 + j;
        f32x4 v = *(const f32x4*)(s + (size_t)(k0 + r) * N + n0 + tx * 4);
        tile[r][tx*4+0] = v[0]; tile[r][tx*4+1] = v[1];
        tile[r][tx*4+2] = v[2]; tile[r][tx*4+3] = v[3];
    }
    __syncthreads();
    #pragma unroll
    for (int j = 0; j < 4; ++j) {
        int n = ty * 4 + j;
        u16x4 w;
        #pragma unroll
        for (int c = 0; c < 4; ++c) w[c] = f2bf(tile[tx*4+c][n]);
        *(u16x4*)(d + (size_t)(n0 - nw0 + n) * K + k0 + tx * 4) = w;
    }
}

// ---------- K1: gating (1 wave per token) ----------
__global__ void __launch_bounds__(64) k_gate(const float* __restrict__ x,
                                             const float* __restrict__ gw,
                                             const float* __restrict__ gb,
                                             int* __restrict__ cnt,
                                             int* __restrict__ tt_idx,
                                             float* __restrict__ tt_w) {
    const int t = blockIdx.x;
    const int lane = threadIdx.x;
    float acc[NE] = {0.f,0.f,0.f,0.f,0.f,0.f,0.f,0.f};
    const float* xr = x + (size_t)t * DM;
    #pragma unroll
    for (int c = 0; c < DM/64; ++c) {
        float xv = xr[lane + 64*c];
        const float* g = gw + (size_t)(lane + 64*c) * NE;
        #pragma unroll
        for (int e = 0; e < NE; ++e) acc[e] += xv * g[e];
    }
    #pragma unroll
    for (int e = 0; e < NE; ++e) {
        #pragma unroll
        for (int off = 32; off >= 1; off >>= 1)
            acc[e] += __shfl_xor(acc[e], off, 64);
    }
    if (lane == 0) {
        float l[NE];
        #pragma unroll
        for (int e = 0; e < NE; ++e) l[e] = acc[e] + gb[e];
        int i0 = 0;
        #pragma unroll
        for (int e = 1; e < NE; ++e) if (l[e] > l[i0]) i0 = e;
        int i1 = (i0 == 0) ? 1 : 0;
        #pragma unroll
        for (int e = 0; e < NE; ++e) if (e != i0 && l[e] > l[i1]) i1 = e;
        float m  = l[i0];
        float w0 = expf(l[i0] - m), w1 = expf(l[i1] - m);
        float s = w0 + w1; w0 /= s; w1 /= s;
        tt_idx[t*2] = i0; tt_idx[t*2+1] = i1;
        tt_w[t*2] = w0;  tt_w[t*2+1] = w1;
        atomicAdd(&cnt[i0], 1); atomicAdd(&cnt[i1], 1);
    }
}

// ---------- K2: pad-aligned expert offsets ----------
__global__ void k_offsets(const int* __restrict__ cnt, int* __restrict__ fill,
                          int* __restrict__ off, int pad) {
    if (threadIdx.x == 0 && blockIdx.x == 0) {
        int a = 0;
        for (int e = 0; e < NE; ++e) {
            off[e] = a;
            a += (cnt[e] + pad - 1) / pad * pad;
            fill[e] = 0;
        }
        off[NE] = a;
    }
}

// ---------- K3: scatter token->slot ----------
__global__ void k_scatter(const int* __restrict__ tt_idx, const float* __restrict__ tt_w,
                          const int* __restrict__ off, int* __restrict__ fill,
                          int* __restrict__ slot_token, float* __restrict__ slot_gate) {
    int t = blockIdx.x * blockDim.x + threadIdx.x;
    if (t >= T_TOKENS) return;
    #pragma unroll
    for (int k = 0; k < 2; ++k) {
        int e = tt_idx[t*2+k];
        int pos = off[e] + atomicAdd(&fill[e], 1);
        slot_token[pos] = t;
        slot_gate[pos]  = tt_w[t*2+k];
    }
}

// ---------- MFMA inner steps ----------
// wave tile 64x64 (wr in units of 64 rows, wc in units of 64 cols)
__device__ __forceinline__ void mma64(const u16* As, const u16* Bs, int lane,
                                      int wr, int wc, f32x4 acc[4][4]) {
    #pragma unroll
    for (int ko = 0; ko < 2; ++ko) {
        s16x8 af[4], bfr[4];
        #pragma unroll
        for (int m = 0; m < 4; ++m) {
            int row = wr*64 + m*16 + (lane & 15);
            int sl = (ko*4 + (lane >> 4)) ^ (row & 7);
            af[m] = *(const s16x8*)&As[row*BK + sl*8];
        }
        #pragma unroll
        for (int n = 0; n < 4; ++n) {
            int col = wc*64 + n*16 + (lane & 15);
            int sl = (ko*4 + (lane >> 4)) ^ (col & 7);
            bfr[n] = *(const s16x8*)&Bs[col*BK + sl*8];
        }
        #pragma unroll
        for (int m = 0; m < 4; ++m)
            #pragma unroll
            for (int n = 0; n < 4; ++n)
                acc[m][n] = __builtin_amdgcn_mfma_f32_16x16x32_bf16(af[m], bfr[n], acc[m][n], 0, 0, 0);
    }
}

// wave tile 64x32 (wc in units of 32 cols)
__device__ __forceinline__ void mma64_n2(const u16* As, const u16* Bs, int lane,
                                         int wr, int wc, f32x4 acc[4][2]) {
    #pragma unroll
    for (int ko = 0; ko < 2; ++ko) {
        s16x8 af[4], bfr[2];
        #pragma unroll
        for (int m = 0; m < 4; ++m) {
            int row = wr*64 + m*16 + (lane & 15);
            int sl = (ko*4 + (lane >> 4)) ^ (row & 7);
            af[m] = *(const s16x8*)&As[row*BK + sl*8];
        }
        #pragma unroll
        for (int n = 0; n < 2; ++n) {
            int col = wc*32 + n*16 + (lane & 15);
            int sl = (ko*4 + (lane >> 4)) ^ (col & 7);
            bfr[n] = *(const s16x8*)&Bs[col*BK + sl*8];
        }
        #pragma unroll
        for (int m = 0; m < 4; ++m)
            #pragma unroll
            for (int n = 0; n < 2; ++n)
                acc[m][n] = __builtin_amdgcn_mfma_f32_16x16x32_bf16(af[m], bfr[n], acc[m][n], 0, 0, 0);
    }
}

// ================== 3-buffer, prefetch-distance-2, one-barrier pipeline ==================
// iter kt: wait vmcnt(6|0) [own stage(kt) landed; stage(kt+1) may fly] -> s_barrier
// [ALL waves' stage(kt) landed; all readers of buf[(kt-1)%3] done] ->
// stage(kt+2 -> buf[(kt+2)%3] == buf[(kt-1)%3], safe] -> MFMA(buf[kt%3]).

// ---------- K4: GEMM1 256x128  h = gelu(x[gather] @ w1t_e^T + b1_e) ----------
__global__ void __launch_bounds__(512, 2) k_ffn1_b16(
    const u16* __restrict__ xbf, const u16* __restrict__ wt,   // wt: [e][n-local][k=DM]
    const float* __restrict__ b1, const int* __restrict__ slot_token,
    const int* __restrict__ off, u16* __restrict__ h, int cb0, int NW)
{
    __shared__ u16 As[3][256*BK];   // 96 KB
    __shared__ u16 Bs[3][128*BK];   // 48 KB
    const int rb = blockIdx.y, cbl = blockIdx.x;
    const int total = off[NE];
    const int r0 = rb * 256;
    if (r0 >= total) return;
    int e = 0;
    while (e < NE-1 && off[e+1] <= r0) e++;
    const u16* Bsrc = wt + (size_t)e * DM * NW;
    const float* be = b1 + (size_t)e * DH;
    const int colbase = (cb0 + cbl) * 128;

    const int tid = threadIdx.x;
    const int lane = tid & 63, wid = tid >> 6;    // 8 waves
    const int wr = wid >> 1, wc = wid & 1;        // 4M x 2N, wave tile 64x64

    const u16* gA[4]; const u16* gB[2];
    #pragma unroll
    for (int i = 0; i < 4; ++i) {
        int row = wid*32 + i*8 + (lane >> 3);               // 0..255
        int g = (lane & 7) ^ (row & 7);
        int tok = slot_token[r0 + row];
        gA[i] = xbf + (size_t)tok * DM + g*8;
    }
    #pragma unroll
    for (int i = 0; i < 2; ++i) {
        int n = wid*16 + i*8 + (lane >> 3);                 // 0..127
        int g = (lane & 7) ^ (n & 7);
        gB[i] = Bsrc + (size_t)(cbl*128 + n) * DM + g*8;
    }

    f32x4 acc[4][4];
    #pragma unroll
    for (int m = 0; m < 4; ++m)
        #pragma unroll
        for (int n = 0; n < 4; ++n) acc[m][n] = (f32x4){0.f,0.f,0.f,0.f};

    #define STG1(buf, kt) do {                                                \
        _Pragma("unroll")                                                     \
        for (int i = 0; i < 4; ++i)                                           \
            GLOAD_LDS16(gA[i] + (kt)*BK, &As[buf][(wid*32 + i*8)*BK]);        \
        _Pragma("unroll")                                                     \
        for (int i = 0; i < 2; ++i)                                           \
            GLOAD_LDS16(gB[i] + (kt)*BK, &Bs[buf][(wid*16 + i*8)*BK]);        \
    } while (0)

    const int NT = DM / BK;   // 16
    STG1(0, 0);
    STG1(1, 1);
    int cur = 0, stg = 2;
    #pragma unroll 1
    for (int kt = 0; kt < NT; ++kt) {
        if (kt + 1 < NT) WAIT_VM6(); else WAIT_VM0();
        __builtin_amdgcn_s_barrier();
        if (kt + 2 < NT) STG1(stg, kt + 2);
        __builtin_amdgcn_s_setprio(1);
        mma64(As[cur], Bs[cur], lane, wr, wc, acc);
        __builtin_amdgcn_s_setprio(0);
        cur = (cur == 2) ? 0 : cur + 1;
        stg = (stg == 2) ? 0 : stg + 1;
    }
    #undef STG1

    #pragma unroll
    for (int n = 0; n < 4; ++n) {
        int col = colbase + wc*64 + n*16 + (lane & 15);
        float bb = be[col];
        #pragma unroll
        for (int m = 0; m < 4; ++m) {
            int rbase = r0 + wr*64 + m*16 + (lane >> 4)*4;
            #pragma unroll
            for (int i = 0; i < 4; ++i) {
                float v = acc[m][n][i] + bb;
                float gv = 0.5f * v * (1.0f + erff(v * 0.70710678118654752f));
                h[(size_t)(rbase + i)*DH + col] = f2bf(gv);
            }
        }
    }
}

// ---------- K5: GEMM2 128x128, 512 thr, same 3-buffer pipeline ----------
__global__ void __launch_bounds__(512, 2) k_ffn2_b16(
    const u16* __restrict__ h, const u16* __restrict__ w2t,    // w2t: [e][n=DM][k=DH]
    const float* __restrict__ b2, const int* __restrict__ slot_token,
    const float* __restrict__ slot_gate, const int* __restrict__ off,
    float* __restrict__ out)
{
    __shared__ u16 As[3][BM*BK];   // 48 KB
    __shared__ u16 Bs[3][BN*BK];   // 48 KB
    const int rb = blockIdx.y, cb = blockIdx.x;
    const int total = off[NE];
    const int r0 = rb * BM;
    if (r0 >= total) return;
    int e = 0;
    while (e < NE-1 && off[e+1] <= r0) e++;
    const u16* Bsrc = w2t + (size_t)e * DH * DM;
    const float* be = b2 + (size_t)e * DM;

    const int tid = threadIdx.x;
    const int lane = tid & 63, wid = tid >> 6;    // 8 waves
    const int wr = wid >> 2, wc = wid & 3;        // 2M x 4N, wave tile 64x32

    const u16* gA[2]; const u16* gB[2];
    #pragma unroll
    for (int i = 0; i < 2; ++i) {
        int row = wid*16 + i*8 + (lane >> 3);               // 0..127
        int g = (lane & 7) ^ (row & 7);
        gA[i] = h + (size_t)(r0 + row) * DH + g*8;
        gB[i] = Bsrc + (size_t)(cb*BN + row) * DH + g*8;
    }

    f32x4 acc[4][2];
    #pragma unroll
    for (int m = 0; m < 4; ++m)
        #pragma unroll
        for (int n = 0; n < 2; ++n) acc[m][n] = (f32x4){0.f,0.f,0.f,0.f};

    #define STG2(buf, kt) do {                                                \
        _Pragma("unroll")                                                     \
        for (int i = 0; i < 2; ++i) {                                         \
            GLOAD_LDS16(gA[i] + (kt)*BK, &As[buf][(wid*16 + i*8)*BK]);        \
            GLOAD_LDS16(gB[i] + (kt)*BK, &Bs[buf][(wid*16 + i*8)*BK]);        \
        }                                                                     \
    } while (0)

    const int NT = DH / BK;   // 64
    STG2(0, 0);
    STG2(1, 1);
    int cur = 0, stg = 2;
    #pragma unroll 1
    for (int kt = 0; kt < NT; ++kt) {
        if (kt + 1 < NT) WAIT_VM4(); else WAIT_VM0();
        __builtin_amdgcn_s_barrier();
        if (kt + 2 < NT) STG2(stg, kt + 2);
        __builtin_amdgcn_s_setprio(1);
        mma64_n2(As[cur], Bs[cur], lane, wr, wc, acc);
        __builtin_amdgcn_s_setprio(0);
        cur = (cur == 2) ? 0 : cur + 1;
        stg = (stg == 2) ? 0 : stg + 1;
    }
    #undef STG2

    float bb[2];
    #pragma unroll
    for (int n = 0; n < 2; ++n) bb[n] = be[cb*BN + wc*32 + n*16 + (lane & 15)];
    #pragma unroll
    for (int m = 0; m < 4; ++m) {
        #pragma unroll
        for (int i = 0; i < 4; ++i) {
            int s = r0 + wr*64 + m*16 + (lane >> 4)*4 + i;
            int tok = slot_token[s];
            float g = slot_gate[s];
            if (g != 0.0f) {
                float* orow = out + (size_t)tok * DM + cb*BN + wc*32;
                #pragma unroll
                for (int n = 0; n < 2; ++n)
                    atomicAdd(orow + n*16 + (lane & 15), g * (acc[m][n][i] + bb[n]));
            }
        }
    }
}

// ================== f32-weight fallback path (round-1 kernels, 128-pad) ==================

__global__ void __launch_bounds__(256) k_ffn1_f32(
    const u16* __restrict__ xbf, const float* __restrict__ w1,
    const float* __restrict__ b1, const int* __restrict__ slot_token,
    const int* __restrict__ off, u16* __restrict__ h)
{
    __shared__ u16 As[BM*BK];
    __shared__ u16 Bs[BN*BK];
    const int rb = blockIdx.y, cb = blockIdx.x;
    const int total = off[NE];
    const int r0 = rb * BM;
    if (r0 >= total) return;
    int e = 0;
    while (e < NE-1 && off[e+1] <= r0) e++;
    const float* Bsrc = w1 + (size_t)e * DM * DH;
    const float* be   = b1 + (size_t)e * DH;

    const int tid = threadIdx.x;
    const int lane = tid & 63, wid = tid >> 6;
    const int wr = wid >> 1, wc = wid & 1;

    const u16* gA[4];
    #pragma unroll
    for (int i = 0; i < 4; ++i) {
        int row = wid*32 + i*8 + (lane >> 3);
        int g = (lane & 7) ^ (row & 7);
        int tok = slot_token[r0 + row];
        gA[i] = xbf + (size_t)tok * DM + g*8;
    }
    const int tc = tid & 31, tr = tid >> 5;
    const float* gB = Bsrc + (size_t)(tr*8) * DH + cb*BN + tc*4;

    f32x4 acc[4][4];
    #pragma unroll
    for (int m = 0; m < 4; ++m)
        #pragma unroll
        for (int n = 0; n < 4; ++n) acc[m][n] = (f32x4){0.f,0.f,0.f,0.f};

    for (int kt = 0; kt < DM/BK; ++kt) {
        #pragma unroll
        for (int i = 0; i < 4; ++i)
            GLOAD_LDS16(gA[i] + kt*BK, &As[(wid*32 + i*8)*BK]);
        f32x4 bv[8];
        #pragma unroll
        for (int j = 0; j < 8; ++j)
            bv[j] = *(const f32x4*)(gB + (size_t)(kt*BK + j) * DH);
        #pragma unroll
        for (int c = 0; c < 4; ++c) {
            int n = tc*4 + c;
            int sl = tr ^ (n & 7);
            s16x8 pk;
            #pragma unroll
            for (int j = 0; j < 8; ++j) pk[j] = (short)f2bf(bv[j][c]);
            *(s16x8*)&Bs[n*BK + sl*8] = pk;
        }
        __syncthreads();
        mma64(As, Bs, lane, wr, wc, acc);
        __syncthreads();
    }
    #pragma unroll
    for (int n = 0; n < 4; ++n) {
        int col = cb*BN + wc*64 + n*16 + (lane & 15);
        float bb = be[col];
        #pragma unroll
        for (int m = 0; m < 4; ++m) {
            int rbase = r0 + wr*64 + m*16 + (lane >> 4)*4;
            #pragma unroll
            for (int i = 0; i < 4; ++i) {
                float v = acc[m][n][i] + bb;
                float gv = 0.5f * v * (1.0f + erff(v * 0.70710678118654752f));
                h[(size_t)(rbase + i)*DH + col] = f2bf(gv);
            }
        }
    }
}

__global__ void __launch_bounds__(256) k_ffn2_f32(
    const u16* __restrict__ h, const float* __restrict__ w2,
    const float* __restrict__ b2, const int* __restrict__ slot_token,
    const float* __restrict__ slot_gate, const int* __restrict__ off,
    float* __restrict__ out)
{
    __shared__ u16 As[BM*BK];
    __shared__ u16 Bs[BN*BK];
    const int rb = blockIdx.y, cb = blockIdx.x;
    const int total = off[NE];
    const int r0 = rb * BM;
    if (r0 >= total) return;
    int e = 0;
    while (e < NE-1 && off[e+1] <= r0) e++;
    const float* Bsrc = w2 + (size_t)e * DH * DM;
    const float* be   = b2 + (size_t)e * DM;

    const int tid = threadIdx.x;
    const int lane = tid & 63, wid = tid >> 6;
    const int wr = wid >> 1, wc = wid & 1;

    const u16* gA[4];
    #pragma unroll
    for (int i = 0; i < 4; ++i) {
        int row = wid*32 + i*8 + (lane >> 3);
        int g = (lane & 7) ^ (row & 7);
        gA[i] = h + (size_t)(r0 + row) * DH + g*8;
    }
    const int tc = tid & 31, tr = tid >> 5;
    const float* gB = Bsrc + (size_t)(tr*8) * DM + cb*BN + tc*4;

    f32x4 acc[4][4];
    #pragma unroll
    for (int m = 0; m < 4; ++m)
        #pragma unroll
        for (int n = 0; n < 4; ++n) acc[m][n] = (f32x4){0.f,0.f,0.f,0.f};

    for (int kt = 0; kt < DH/BK; ++kt) {
        #pragma unroll
        for (int i = 0; i < 4; ++i)
            GLOAD_LDS16(gA[i] + kt*BK, &As[(wid*32 + i*8)*BK]);
        f32x4 bv[8];
        #pragma unroll
        for (int j = 0; j < 8; ++j)
            bv[j] = *(const f32x4*)(gB + (size_t)(kt*BK + j) * DM);
        #pragma unroll
        for (int c = 0; c < 4; ++c) {
            int n = tc*4 + c;
            int sl = tr ^ (n & 7);
            s16x8 pk;
            #pragma unroll
            for (int j = 0; j < 8; ++j) pk[j] = (short)f2bf(bv[j][c]);
            *(s16x8*)&Bs[n*BK + sl*8] = pk;
        }
        __syncthreads();
        mma64(As, Bs, lane, wr, wc, acc);
        __syncthreads();
    }
    float bb[4];
    #pragma unroll
    for (int n = 0; n < 4; ++n) bb[n] = be[cb*BN + wc*64 + n*16 + (lane & 15)];
    #pragma unroll
    for (int m = 0; m < 4; ++m) {
        #pragma unroll
        for (int i = 0; i < 4; ++i) {
            int s = r0 + wr*64 + m*16 + (lane >> 4)*4 + i;
            int tok = slot_token[s];
            float g = slot_gate[s];
            if (g != 0.0f) {
                float* orow = out + (size_t)tok * DM + cb*BN + wc*64;
                #pragma unroll
                for (int n = 0; n < 4; ++n)
                    atomicAdd(orow + n*16 + (lane & 15), g * (acc[m][n][i] + bb[n]));
            }
        }
    }
}

extern "C" void kernel_launch(void* const* d_in, const int* in_sizes, int n_in,
                              void* d_out, int out_size, void* d_ws, size_t ws_size,
                              hipStream_t stream)
{
    (void)in_sizes; (void)n_in; (void)out_size;
    const float* x  = (const float*)d_in[0];
    const float* gw = (const float*)d_in[1];
    const float* gb = (const float*)d_in[2];
    const float* w1 = (const float*)d_in[3];
    const float* b1 = (const float*)d_in[4];
    const float* w2 = (const float*)d_in[5];
    const float* b2 = (const float*)d_in[6];
    float* out = (float*)d_out;
    char* ws = (char*)d_ws;

    // layout: xbf 4MiB | h 48MiB (6144x4096 bf16) | ctrl arrays | wt (64 or 32 MiB)
    const size_t OFF_XBF = 0;
    const size_t OFF_H   = 4194304;
    const size_t OFF_ST  = OFF_H + (size_t)MAXS2 * DH * 2;     // 54525952
    const size_t OFF_SG  = OFF_ST + MAXS2 * 4;
    const size_t OFF_TI  = OFF_SG + MAXS2 * 4;
    const size_t OFF_TW  = OFF_TI + T_TOKENS * 2 * 4;
    const size_t OFF_CT  = OFF_TW + T_TOKENS * 2 * 4;
    const size_t OFF_WT  = (OFF_CT + 128 + 255) & ~(size_t)255;
    const size_t NEED_FULL = OFF_WT + (size_t)NE * DM * DH * 2;          // ~116 MiB
    const size_t NEED_HALF = OFF_WT + (size_t)NE * DM * (DH/2) * 2;      // ~84 MiB

    if (ws_size >= NEED_HALF) {
        u16*   xbf        = (u16*)(ws + OFF_XBF);
        u16*   h          = (u16*)(ws + OFF_H);
        int*   slot_token = (int*)(ws + OFF_ST);
        float* slot_gate  = (float*)(ws + OFF_SG);
        int*   tt_idx     = (int*)(ws + OFF_TI);
        float* tt_w       = (float*)(ws + OFF_TW);
        int*   ctrl       = (int*)(ws + OFF_CT);
        u16*   wt         = (u16*)(ws + OFF_WT);
        int* cnt = ctrl; int* fill = ctrl + 8; int* offs = ctrl + 16;
        const int full = (ws_size >= NEED_FULL);

        hipMemsetAsync(slot_token, 0, 2 * MAXS2 * 4, stream);   // tokens + gates (pads -> gate 0)
        hipMemsetAsync(out, 0, (size_t)T_TOKENS * DM * sizeof(float), stream);

        k_convert<<<(T_TOKENS*DM/8 + 255)/256, 256, 0, stream>>>(x, xbf, ctrl);
        k_gate<<<T_TOKENS, 64, 0, stream>>>(x, gw, gb, cnt, tt_idx, tt_w);
        k_offsets<<<1, 64, 0, stream>>>(cnt, fill, offs, PAD2);
        k_scatter<<<(T_TOKENS + 255)/256, 256, 0, stream>>>(tt_idx, tt_w, offs, fill,
                                                            slot_token, slot_gate);
        if (full) {
            // w1t[e][n][k], all DH cols
            k_transpose<<<dim3(DH/64, DM/64, NE), 256, 0, stream>>>(w1, wt, DM, DH, 0, DH);
            k_ffn1_b16<<<dim3(DH/128, RB1), 512, 0, stream>>>(xbf, wt, b1, slot_token, offs, h, 0, DH);
        } else {
            // two half-windows of w1t (32 MiB region)
            k_transpose<<<dim3(DH/128, DM/64, NE), 256, 0, stream>>>(w1, wt, DM, DH, 0, DH/2);
            k_ffn1_b16<<<dim3(DH/256, RB1), 512, 0, stream>>>(xbf, wt, b1, slot_token, offs, h, 0, DH/2);
            k_transpose<<<dim3(DH/128, DM/64, NE), 256, 0, stream>>>(w1, wt, DM, DH, DH/2, DH/2);
            k_ffn1_b16<<<dim3(DH/256, RB1), 512, 0, stream>>>(xbf, wt, b1, slot_token, offs, h, DH/256, DH/2);
        }
        // w2t[e][n=DM][k=DH]  (16 MiB, fits either region)
        k_transpose<<<dim3(DM/64, DH/64, NE), 256, 0, stream>>>(w2, wt, DH, DM, 0, DM);
        k_ffn2_b16<<<dim3(DM/BN, RB2), 512, 0, stream>>>(h, wt, b2, slot_token, slot_gate, offs, out);
    } else {
        // f32-weight fallback (round-1 path, 128-pad)
        u16*   xbf        = (u16*)(ws);
        u16*   h          = (u16*)(ws + 4194304);
        int*   slot_token = (int*)(ws + 46137344);
        float* slot_gate  = (float*)(ws + 46157824);
        int*   tt_idx     = (int*)(ws + 46178304);
        float* tt_w       = (float*)(ws + 46194688);
        int*   ctrl       = (int*)(ws + 46211072);
        int* cnt = ctrl; int* fill = ctrl + 8; int* offs = ctrl + 16;

        hipMemsetAsync(slot_token, 0, 2 * MAXSLOTS * 4, stream);
        hipMemsetAsync(out, 0, (size_t)T_TOKENS * DM * sizeof(float), stream);

        k_convert<<<(T_TOKENS*DM/8 + 255)/256, 256, 0, stream>>>(x, xbf, ctrl);
        k_gate<<<T_TOKENS, 64, 0, stream>>>(x, gw, gb, cnt, tt_idx, tt_w);
        k_offsets<<<1, 64, 0, stream>>>(cnt, fill, offs, BM);
        k_scatter<<<(T_TOKENS + 255)/256, 256, 0, stream>>>(tt_idx, tt_w, offs, fill,
                                                            slot_token, slot_gate);
        k_ffn1_f32<<<dim3(DH/BN, ROWBLK), 256, 0, stream>>>(xbf, w1, b1, slot_token, offs, h);
        k_ffn2_f32<<<dim3(DM/BN, ROWBLK), 256, 0, stream>>>(h, w2, b2, slot_token, slot_gate, offs, out);
    }
}

// Round 10
// 335.784 us; speedup vs baseline: 1.1494x; 1.1494x over previous
//
#include <hip/hip_runtime.h>
#include <stdint.h>

typedef unsigned short u16;
typedef __attribute__((ext_vector_type(8))) short s16x8;   // 8 bf16 (4 VGPRs)
typedef __attribute__((ext_vector_type(8))) u16  u16x8;
typedef __attribute__((ext_vector_type(4))) u16  u16x4;
typedef __attribute__((ext_vector_type(4))) float f32x4;

#define T_TOKENS 2048
#define DM 1024
#define DH 4096
#define NE 8
#define BK 64
#define BM 128
#define BN 128
#define MAXSLOTS (T_TOKENS*2 + NE*BM)   // 5120
#define ROWBLK (MAXSLOTS/BM)            // 40

__device__ __forceinline__ u16 f2bf(float f) {
    union { float ff; uint32_t u; } v; v.ff = f;
    uint32_t r = v.u + 0x7fffu + ((v.u >> 16) & 1u);   // RNE
    return (u16)(r >> 16);
}

#define GLOAD_LDS16(gsrc, ldst) \
    __builtin_amdgcn_global_load_lds((const __attribute__((address_space(1))) uint32_t*)(gsrc), \
                                     (__attribute__((address_space(3))) uint32_t*)(ldst), 16, 0, 0)

// counted waits: 8 loads per stage; next tile's 8 stay in flight while computing current
#define WAIT_VM8() asm volatile("s_waitcnt vmcnt(8)" ::: "memory")
#define WAIT_VM0() asm volatile("s_waitcnt vmcnt(0)" ::: "memory")

// ---------- K0: convert x f32 -> bf16, zero control ints ----------
__global__ void k_convert(const float* __restrict__ x, u16* __restrict__ xbf,
                          int* __restrict__ ctrl) {
    int i = blockIdx.x * blockDim.x + threadIdx.x;
    const f32x4* xv = (const f32x4*)x;
    f32x4 a = xv[2*i], b = xv[2*i+1];
    u16x8 o;
    o[0]=f2bf(a[0]); o[1]=f2bf(a[1]); o[2]=f2bf(a[2]); o[3]=f2bf(a[3]);
    o[4]=f2bf(b[0]); o[5]=f2bf(b[1]); o[6]=f2bf(b[2]); o[7]=f2bf(b[3]);
    ((u16x8*)xbf)[i] = o;
    if (blockIdx.x == 0 && threadIdx.x < 32) ctrl[threadIdx.x] = 0;
}

// ---------- K0b: windowed transpose + f32->bf16  dst[e][(n-nw0)][k] = src[e][k][n] ----------
__global__ void __launch_bounds__(256) k_transpose(const float* __restrict__ src,
                                                   u16* __restrict__ dst,
                                                   int K, int N, int nw0, int NW) {
    __shared__ float tile[64][65];
    const int e = blockIdx.z;
    const int n0 = nw0 + blockIdx.x * 64, k0 = blockIdx.y * 64;
    const float* s = src + (size_t)e * K * N;
    u16* d = dst + (size_t)e * K * NW;
    const int tx = threadIdx.x & 15, ty = threadIdx.x >> 4;
    #pragma unroll
    for (int j = 0; j < 4; ++j) {
        int r = ty * 4 + j;
        f32x4 v = *(const f32x4*)(s + (size_t)(k0 + r) * N + n0 + tx * 4);
        tile[r][tx*4+0] = v[0]; tile[r][tx*4+1] = v[1];
        tile[r][tx*4+2] = v[2]; tile[r][tx*4+3] = v[3];
    }
    __syncthreads();
    #pragma unroll
    for (int j = 0; j < 4; ++j) {
        int n = ty * 4 + j;
        u16x4 w;
        #pragma unroll
        for (int c = 0; c < 4; ++c) w[c] = f2bf(tile[tx*4+c][n]);
        *(u16x4*)(d + (size_t)(n0 - nw0 + n) * K + k0 + tx * 4) = w;
    }
}

// ---------- K1: gating (1 wave per token) ----------
__global__ void __launch_bounds__(64) k_gate(const float* __restrict__ x,
                                             const float* __restrict__ gw,
                                             const float* __restrict__ gb,
                                             int* __restrict__ cnt,
                                             int* __restrict__ tt_idx,
                                             float* __restrict__ tt_w) {
    const int t = blockIdx.x;
    const int lane = threadIdx.x;
    float acc[NE] = {0.f,0.f,0.f,0.f,0.f,0.f,0.f,0.f};
    const float* xr = x + (size_t)t * DM;
    #pragma unroll
    for (int c = 0; c < DM/64; ++c) {
        float xv = xr[lane + 64*c];
        const float* g = gw + (size_t)(lane + 64*c) * NE;
        #pragma unroll
        for (int e = 0; e < NE; ++e) acc[e] += xv * g[e];
    }
    #pragma unroll
    for (int e = 0; e < NE; ++e) {
        #pragma unroll
        for (int off = 32; off >= 1; off >>= 1)
            acc[e] += __shfl_xor(acc[e], off, 64);
    }
    if (lane == 0) {
        float l[NE];
        #pragma unroll
        for (int e = 0; e < NE; ++e) l[e] = acc[e] + gb[e];
        int i0 = 0;
        #pragma unroll
        for (int e = 1; e < NE; ++e) if (l[e] > l[i0]) i0 = e;
        int i1 = (i0 == 0) ? 1 : 0;
        #pragma unroll
        for (int e = 0; e < NE; ++e) if (e != i0 && l[e] > l[i1]) i1 = e;
        float m  = l[i0];
        float w0 = expf(l[i0] - m), w1 = expf(l[i1] - m);
        float s = w0 + w1; w0 /= s; w1 /= s;
        tt_idx[t*2] = i0; tt_idx[t*2+1] = i1;
        tt_w[t*2] = w0;  tt_w[t*2+1] = w1;
        atomicAdd(&cnt[i0], 1); atomicAdd(&cnt[i1], 1);
    }
}

// ---------- K2: pad-aligned expert offsets ----------
__global__ void k_offsets(const int* __restrict__ cnt, int* __restrict__ fill,
                          int* __restrict__ off, int pad) {
    if (threadIdx.x == 0 && blockIdx.x == 0) {
        int a = 0;
        for (int e = 0; e < NE; ++e) {
            off[e] = a;
            a += (cnt[e] + pad - 1) / pad * pad;
            fill[e] = 0;
        }
        off[NE] = a;
    }
}

// ---------- K3: scatter token->slot ----------
__global__ void k_scatter(const int* __restrict__ tt_idx, const float* __restrict__ tt_w,
                          const int* __restrict__ off, int* __restrict__ fill,
                          int* __restrict__ slot_token, float* __restrict__ slot_gate) {
    int t = blockIdx.x * blockDim.x + threadIdx.x;
    if (t >= T_TOKENS) return;
    #pragma unroll
    for (int k = 0; k < 2; ++k) {
        int e = tt_idx[t*2+k];
        int pos = off[e] + atomicAdd(&fill[e], 1);
        slot_token[pos] = t;
        slot_gate[pos]  = tt_w[t*2+k];
    }
}

// ---------- K3b: init out with gate-weighted biases (replaces memset; ffn2 adds g*acc) ----------
__global__ void __launch_bounds__(256) k_binit(const float* __restrict__ b2,
                                               const int* __restrict__ tt_idx,
                                               const float* __restrict__ tt_w,
                                               float* __restrict__ out) {
    const int t = blockIdx.x;
    const int d = threadIdx.x * 4;
    const int e0 = tt_idx[t*2], e1 = tt_idx[t*2+1];
    const float g0 = tt_w[t*2], g1 = tt_w[t*2+1];
    f32x4 b0 = *(const f32x4*)(b2 + (size_t)e0 * DM + d);
    f32x4 b1 = *(const f32x4*)(b2 + (size_t)e1 * DM + d);
    f32x4 o;
    #pragma unroll
    for (int c = 0; c < 4; ++c) o[c] = g0 * b0[c] + g1 * b1[c];
    *(f32x4*)(out + (size_t)t * DM + d) = o;
}

// ---------- MFMA inner step: 128x128, 4 waves, wave tile 64x64 ----------
__device__ __forceinline__ void mma64(const u16* As, const u16* Bs, int lane,
                                      int wr, int wc, f32x4 acc[4][4]) {
    #pragma unroll
    for (int ko = 0; ko < 2; ++ko) {
        s16x8 af[4], bfr[4];
        #pragma unroll
        for (int m = 0; m < 4; ++m) {
            int row = wr*64 + m*16 + (lane & 15);
            int sl = (ko*4 + (lane >> 4)) ^ (row & 7);
            af[m] = *(const s16x8*)&As[row*BK + sl*8];
        }
        #pragma unroll
        for (int n = 0; n < 4; ++n) {
            int col = wc*64 + n*16 + (lane & 15);
            int sl = (ko*4 + (lane >> 4)) ^ (col & 7);
            bfr[n] = *(const s16x8*)&Bs[col*BK + sl*8];
        }
        #pragma unroll
        for (int m = 0; m < 4; ++m)
            #pragma unroll
            for (int n = 0; n < 4; ++n)
                acc[m][n] = __builtin_amdgcn_mfma_f32_16x16x32_bf16(af[m], bfr[n], acc[m][n], 0, 0, 0);
    }
}

// ================== best-measured structure: 2-buffer, counted vmcnt(8), 2 barriers ==================
// iter kt: vm8 (own tile-kt loads done; kt+1 in flight) -> s_barrier (all waves' kt landed)
// -> MFMA(buf kt&1) -> s_barrier (all readers done) -> stage(kt+2 -> buf kt&1).

// ---------- K4: GEMM1 128x128  h = gelu(x[gather] @ w1t_e^T + b1_e)  [round-5 config, 118 us] ----------
__global__ void __launch_bounds__(256) k_ffn1_b16(
    const u16* __restrict__ xbf, const u16* __restrict__ wt,   // wt: [e][n-local][k=DM]
    const float* __restrict__ b1, const int* __restrict__ slot_token,
    const int* __restrict__ off, u16* __restrict__ h, int cb0, int NW)
{
    __shared__ u16 As[2][BM*BK];   // 32 KB
    __shared__ u16 Bs[2][BN*BK];   // 32 KB
    const int rb = blockIdx.y, cbl = blockIdx.x;
    const int total = off[NE];
    const int r0 = rb * BM;
    if (r0 >= total) return;
    int e = 0;
    while (e < NE-1 && off[e+1] <= r0) e++;
    const u16* Bsrc = wt + (size_t)e * DM * NW;
    const float* be = b1 + (size_t)e * DH;
    const int colbase = (cb0 + cbl) * BN;

    const int tid = threadIdx.x;
    const int lane = tid & 63, wid = tid >> 6;
    const int wr = wid >> 1, wc = wid & 1;

    const u16* gA[4]; const u16* gB[4];
    #pragma unroll
    for (int i = 0; i < 4; ++i) {
        int row = wid*32 + i*8 + (lane >> 3);
        int g = (lane & 7) ^ (row & 7);
        int tok = slot_token[r0 + row];
        gA[i] = xbf + (size_t)tok * DM + g*8;
        gB[i] = Bsrc + (size_t)(cbl*BN + row) * DM + g*8;
    }

    f32x4 acc[4][4];
    #pragma unroll
    for (int m = 0; m < 4; ++m)
        #pragma unroll
        for (int n = 0; n < 4; ++n) acc[m][n] = (f32x4){0.f,0.f,0.f,0.f};

    #define STG1(buf, kt) do {                                                \
        _Pragma("unroll")                                                     \
        for (int i = 0; i < 4; ++i) {                                         \
            GLOAD_LDS16(gA[i] + (kt)*BK, &As[buf][(wid*32 + i*8)*BK]);        \
            GLOAD_LDS16(gB[i] + (kt)*BK, &Bs[buf][(wid*32 + i*8)*BK]);        \
        }                                                                     \
    } while (0)

    const int NT = DM / BK;   // 16
    STG1(0, 0);
    STG1(1, 1);
    #pragma unroll 1
    for (int kt = 0; kt < NT; ++kt) {
        if (kt + 1 < NT) WAIT_VM8(); else WAIT_VM0();
        __builtin_amdgcn_s_barrier();
        __builtin_amdgcn_s_setprio(1);
        mma64(As[kt & 1], Bs[kt & 1], lane, wr, wc, acc);
        __builtin_amdgcn_s_setprio(0);
        __builtin_amdgcn_s_barrier();
        if (kt + 2 < NT) STG1(kt & 1, kt + 2);
    }
    #undef STG1

    #pragma unroll
    for (int n = 0; n < 4; ++n) {
        int col = colbase + wc*64 + n*16 + (lane & 15);
        float bb = be[col];
        #pragma unroll
        for (int m = 0; m < 4; ++m) {
            int rbase = r0 + wr*64 + m*16 + (lane >> 4)*4;
            #pragma unroll
            for (int i = 0; i < 4; ++i) {
                float v = acc[m][n][i] + bb;
                float gv = 0.5f * v * (1.0f + erff(v * 0.70710678118654752f));
                h[(size_t)(rbase + i)*DH + col] = f2bf(gv);
            }
        }
    }
}

// ---------- K5: GEMM2 128x128 split-K=2  out[tok] += gate * acc  (bias via k_binit) ----------
__global__ void __launch_bounds__(256) k_ffn2_b16(
    const u16* __restrict__ h, const u16* __restrict__ w2t,    // w2t: [e][n=DM][k=DH]
    const int* __restrict__ slot_token, const float* __restrict__ slot_gate,
    const int* __restrict__ off, float* __restrict__ out)
{
    __shared__ u16 As[2][BM*BK];
    __shared__ u16 Bs[2][BN*BK];
    const int rb = blockIdx.y, cb = blockIdx.x, kz = blockIdx.z;
    const int total = off[NE];
    const int r0 = rb * BM;
    if (r0 >= total) return;
    int e = 0;
    while (e < NE-1 && off[e+1] <= r0) e++;
    const u16* Bsrc = w2t + (size_t)e * DH * DM;
    const int k0 = kz * (DH/2);      // K range [k0, k0+2048)

    const int tid = threadIdx.x;
    const int lane = tid & 63, wid = tid >> 6;
    const int wr = wid >> 1, wc = wid & 1;

    const u16* gA[4]; const u16* gB[4];
    #pragma unroll
    for (int i = 0; i < 4; ++i) {
        int row = wid*32 + i*8 + (lane >> 3);
        int g = (lane & 7) ^ (row & 7);
        gA[i] = h + (size_t)(r0 + row) * DH + k0 + g*8;
        gB[i] = Bsrc + (size_t)(cb*BN + row) * DH + k0 + g*8;
    }

    f32x4 acc[4][4];
    #pragma unroll
    for (int m = 0; m < 4; ++m)
        #pragma unroll
        for (int n = 0; n < 4; ++n) acc[m][n] = (f32x4){0.f,0.f,0.f,0.f};

    #define STG2(buf, kt) do {                                                \
        _Pragma("unroll")                                                     \
        for (int i = 0; i < 4; ++i) {                                         \
            GLOAD_LDS16(gA[i] + (kt)*BK, &As[buf][(wid*32 + i*8)*BK]);        \
            GLOAD_LDS16(gB[i] + (kt)*BK, &Bs[buf][(wid*32 + i*8)*BK]);        \
        }                                                                     \
    } while (0)

    const int NT = DH / BK / 2;   // 32
    STG2(0, 0);
    STG2(1, 1);
    #pragma unroll 1
    for (int kt = 0; kt < NT; ++kt) {
        if (kt + 1 < NT) WAIT_VM8(); else WAIT_VM0();
        __builtin_amdgcn_s_barrier();
        __builtin_amdgcn_s_setprio(1);
        mma64(As[kt & 1], Bs[kt & 1], lane, wr, wc, acc);
        __builtin_amdgcn_s_setprio(0);
        __builtin_amdgcn_s_barrier();
        if (kt + 2 < NT) STG2(kt & 1, kt + 2);
    }
    #undef STG2

    // 4 commutative f32 atomics per out element (2 experts x 2 kz); pad slots gate==0
    #pragma unroll
    for (int m = 0; m < 4; ++m) {
        #pragma unroll
        for (int i = 0; i < 4; ++i) {
            int s = r0 + wr*64 + m*16 + (lane >> 4)*4 + i;
            int tok = slot_token[s];
            float g = slot_gate[s];
            if (g != 0.0f) {
                float* orow = out + (size_t)tok * DM + cb*BN + wc*64;
                #pragma unroll
                for (int n = 0; n < 4; ++n)
                    atomicAdd(orow + n*16 + (lane & 15), g * acc[m][n][i]);
            }
        }
    }
}

// ================== f32-weight fallback path ==================

__global__ void __launch_bounds__(256) k_ffn1_f32(
    const u16* __restrict__ xbf, const float* __restrict__ w1,
    const float* __restrict__ b1, const int* __restrict__ slot_token,
    const int* __restrict__ off, u16* __restrict__ h)
{
    __shared__ u16 As[BM*BK];
    __shared__ u16 Bs[BN*BK];
    const int rb = blockIdx.y, cb = blockIdx.x;
    const int total = off[NE];
    const int r0 = rb * BM;
    if (r0 >= total) return;
    int e = 0;
    while (e < NE-1 && off[e+1] <= r0) e++;
    const float* Bsrc = w1 + (size_t)e * DM * DH;
    const float* be   = b1 + (size_t)e * DH;

    const int tid = threadIdx.x;
    const int lane = tid & 63, wid = tid >> 6;
    const int wr = wid >> 1, wc = wid & 1;

    const u16* gA[4];
    #pragma unroll
    for (int i = 0; i < 4; ++i) {
        int row = wid*32 + i*8 + (lane >> 3);
        int g = (lane & 7) ^ (row & 7);
        int tok = slot_token[r0 + row];
        gA[i] = xbf + (size_t)tok * DM + g*8;
    }
    const int tc = tid & 31, tr = tid >> 5;
    const float* gB = Bsrc + (size_t)(tr*8) * DH + cb*BN + tc*4;

    f32x4 acc[4][4];
    #pragma unroll
    for (int m = 0; m < 4; ++m)
        #pragma unroll
        for (int n = 0; n < 4; ++n) acc[m][n] = (f32x4){0.f,0.f,0.f,0.f};

    for (int kt = 0; kt < DM/BK; ++kt) {
        #pragma unroll
        for (int i = 0; i < 4; ++i)
            GLOAD_LDS16(gA[i] + kt*BK, &As[(wid*32 + i*8)*BK]);
        f32x4 bv[8];
        #pragma unroll
        for (int j = 0; j < 8; ++j)
            bv[j] = *(const f32x4*)(gB + (size_t)(kt*BK + j) * DH);
        #pragma unroll
        for (int c = 0; c < 4; ++c) {
            int n = tc*4 + c;
            int sl = tr ^ (n & 7);
            s16x8 pk;
            #pragma unroll
            for (int j = 0; j < 8; ++j) pk[j] = (short)f2bf(bv[j][c]);
            *(s16x8*)&Bs[n*BK + sl*8] = pk;
        }
        __syncthreads();
        mma64(As, Bs, lane, wr, wc, acc);
        __syncthreads();
    }
    #pragma unroll
    for (int n = 0; n < 4; ++n) {
        int col = cb*BN + wc*64 + n*16 + (lane & 15);
        float bb = be[col];
        #pragma unroll
        for (int m = 0; m < 4; ++m) {
            int rbase = r0 + wr*64 + m*16 + (lane >> 4)*4;
            #pragma unroll
            for (int i = 0; i < 4; ++i) {
                float v = acc[m][n][i] + bb;
                float gv = 0.5f * v * (1.0f + erff(v * 0.70710678118654752f));
                h[(size_t)(rbase + i)*DH + col] = f2bf(gv);
            }
        }
    }
}

__global__ void __launch_bounds__(256) k_ffn2_f32(
    const u16* __restrict__ h, const float* __restrict__ w2,
    const float* __restrict__ b2, const int* __restrict__ slot_token,
    const float* __restrict__ slot_gate, const int* __restrict__ off,
    float* __restrict__ out)
{
    __shared__ u16 As[BM*BK];
    __shared__ u16 Bs[BN*BK];
    const int rb = blockIdx.y, cb = blockIdx.x;
    const int total = off[NE];
    const int r0 = rb * BM;
    if (r0 >= total) return;
    int e = 0;
    while (e < NE-1 && off[e+1] <= r0) e++;
    const float* Bsrc = w2 + (size_t)e * DH * DM;
    const float* be   = b2 + (size_t)e * DM;

    const int tid = threadIdx.x;
    const int lane = tid & 63, wid = tid >> 6;
    const int wr = wid >> 1, wc = wid & 1;

    const u16* gA[4];
    #pragma unroll
    for (int i = 0; i < 4; ++i) {
        int row = wid*32 + i*8 + (lane >> 3);
        int g = (lane & 7) ^ (row & 7);
        gA[i] = h + (size_t)(r0 + row) * DH + g*8;
    }
    const int tc = tid & 31, tr = tid >> 5;
    const float* gB = Bsrc + (size_t)(tr*8) * DM + cb*BN + tc*4;

    f32x4 acc[4][4];
    #pragma unroll
    for (int m = 0; m < 4; ++m)
        #pragma unroll
        for (int n = 0; n < 4; ++n) acc[m][n] = (f32x4){0.f,0.f,0.f,0.f};

    for (int kt = 0; kt < DH/BK; ++kt) {
        #pragma unroll
        for (int i = 0; i < 4; ++i)
            GLOAD_LDS16(gA[i] + kt*BK, &As[(wid*32 + i*8)*BK]);
        f32x4 bv[8];
        #pragma unroll
        for (int j = 0; j < 8; ++j)
            bv[j] = *(const f32x4*)(gB + (size_t)(kt*BK + j) * DM);
        #pragma unroll
        for (int c = 0; c < 4; ++c) {
            int n = tc*4 + c;
            int sl = tr ^ (n & 7);
            s16x8 pk;
            #pragma unroll
            for (int j = 0; j < 8; ++j) pk[j] = (short)f2bf(bv[j][c]);
            *(s16x8*)&Bs[n*BK + sl*8] = pk;
        }
        __syncthreads();
        mma64(As, Bs, lane, wr, wc, acc);
        __syncthreads();
    }
    float bb[4];
    #pragma unroll
    for (int n = 0; n < 4; ++n) bb[n] = be[cb*BN + wc*64 + n*16 + (lane & 15)];
    #pragma unroll
    for (int m = 0; m < 4; ++m) {
        #pragma unroll
        for (int i = 0; i < 4; ++i) {
            int s = r0 + wr*64 + m*16 + (lane >> 4)*4 + i;
            int tok = slot_token[s];
            float g = slot_gate[s];
            if (g != 0.0f) {
                float* orow = out + (size_t)tok * DM + cb*BN + wc*64;
                #pragma unroll
                for (int n = 0; n < 4; ++n)
                    atomicAdd(orow + n*16 + (lane & 15), g * (acc[m][n][i] + bb[n]));
            }
        }
    }
}

extern "C" void kernel_launch(void* const* d_in, const int* in_sizes, int n_in,
                              void* d_out, int out_size, void* d_ws, size_t ws_size,
                              hipStream_t stream)
{
    (void)in_sizes; (void)n_in; (void)out_size;
    const float* x  = (const float*)d_in[0];
    const float* gw = (const float*)d_in[1];
    const float* gb = (const float*)d_in[2];
    const float* w1 = (const float*)d_in[3];
    const float* b1 = (const float*)d_in[4];
    const float* w2 = (const float*)d_in[5];
    const float* b2 = (const float*)d_in[6];
    float* out = (float*)d_out;
    char* ws = (char*)d_ws;

    // layout: xbf 4MiB | h 40MiB (5120x4096 bf16) | ctrl arrays | wt (64 or 32 MiB)
    const size_t OFF_XBF = 0;
    const size_t OFF_H   = 4194304;
    const size_t OFF_ST  = OFF_H + (size_t)MAXSLOTS * DH * 2;  // 46137344
    const size_t OFF_SG  = OFF_ST + MAXSLOTS * 4;
    const size_t OFF_TI  = OFF_SG + MAXSLOTS * 4;
    const size_t OFF_TW  = OFF_TI + T_TOKENS * 2 * 4;
    const size_t OFF_CT  = OFF_TW + T_TOKENS * 2 * 4;
    const size_t OFF_WT  = (OFF_CT + 128 + 255) & ~(size_t)255;
    const size_t NEED_FULL = OFF_WT + (size_t)NE * DM * DH * 2;          // ~108.1 MiB
    const size_t NEED_HALF = OFF_WT + (size_t)NE * DM * (DH/2) * 2;      // ~76.1 MiB

    if (ws_size >= NEED_HALF) {
        u16*   xbf        = (u16*)(ws + OFF_XBF);
        u16*   h          = (u16*)(ws + OFF_H);
        int*   slot_token = (int*)(ws + OFF_ST);
        float* slot_gate  = (float*)(ws + OFF_SG);
        int*   tt_idx     = (int*)(ws + OFF_TI);
        float* tt_w       = (float*)(ws + OFF_TW);
        int*   ctrl       = (int*)(ws + OFF_CT);
        u16*   wt         = (u16*)(ws + OFF_WT);
        int* cnt = ctrl; int* fill = ctrl + 8; int* offs = ctrl + 16;
        const int full = (ws_size >= NEED_FULL);

        hipMemsetAsync(slot_token, 0, 2 * MAXSLOTS * 4, stream);   // tokens + gates (pads -> gate 0)

        k_convert<<<(T_TOKENS*DM/8 + 255)/256, 256, 0, stream>>>(x, xbf, ctrl);
        k_gate<<<T_TOKENS, 64, 0, stream>>>(x, gw, gb, cnt, tt_idx, tt_w);
        k_offsets<<<1, 64, 0, stream>>>(cnt, fill, offs, BM);
        k_scatter<<<(T_TOKENS + 255)/256, 256, 0, stream>>>(tt_idx, tt_w, offs, fill,
                                                            slot_token, slot_gate);
        k_binit<<<T_TOKENS, 256, 0, stream>>>(b2, tt_idx, tt_w, out);

        if (full) {
            k_transpose<<<dim3(DH/64, DM/64, NE), 256, 0, stream>>>(w1, wt, DM, DH, 0, DH);
            k_ffn1_b16<<<dim3(DH/BN, ROWBLK), 256, 0, stream>>>(xbf, wt, b1, slot_token, offs, h, 0, DH);
        } else {
            k_transpose<<<dim3(DH/128, DM/64, NE), 256, 0, stream>>>(w1, wt, DM, DH, 0, DH/2);
            k_ffn1_b16<<<dim3(DH/256, ROWBLK), 256, 0, stream>>>(xbf, wt, b1, slot_token, offs, h, 0, DH/2);
            k_transpose<<<dim3(DH/128, DM/64, NE), 256, 0, stream>>>(w1, wt, DM, DH, DH/2, DH/2);
            k_ffn1_b16<<<dim3(DH/256, ROWBLK), 256, 0, stream>>>(xbf, wt, b1, slot_token, offs, h, DH/256, DH/2);
        }
        // w2t[e][n=DM][k=DH]
        k_transpose<<<dim3(DM/64, DH/64, NE), 256, 0, stream>>>(w2, wt, DH, DM, 0, DM);
        k_ffn2_b16<<<dim3(DM/BN, ROWBLK, 2), 256, 0, stream>>>(h, wt, slot_token, slot_gate, offs, out);
    } else {
        // f32-weight fallback
        u16*   xbf        = (u16*)(ws);
        u16*   h          = (u16*)(ws + OFF_H);
        int*   slot_token = (int*)(ws + OFF_ST);
        float* slot_gate  = (float*)(ws + OFF_SG);
        int*   tt_idx     = (int*)(ws + OFF_TI);
        float* tt_w       = (float*)(ws + OFF_TW);
        int*   ctrl       = (int*)(ws + OFF_CT);
        int* cnt = ctrl; int* fill = ctrl + 8; int* offs = ctrl + 16;

        hipMemsetAsync(slot_token, 0, 2 * MAXSLOTS * 4, stream);
        hipMemsetAsync(out, 0, (size_t)T_TOKENS * DM * sizeof(float), stream);

        k_convert<<<(T_TOKENS*DM/8 + 255)/256, 256, 0, stream>>>(x, xbf, ctrl);
        k_gate<<<T_TOKENS, 64, 0, stream>>>(x, gw, gb, cnt, tt_idx, tt_w);
        k_offsets<<<1, 64, 0, stream>>>(cnt, fill, offs, BM);
        k_scatter<<<(T_TOKENS + 255)/256, 256, 0, stream>>>(tt_idx, tt_w, offs, fill,
                                                            slot_token, slot_gate);
        k_ffn1_f32<<<dim3(DH/BN, ROWBLK), 256, 0, stream>>>(xbf, w1, b1, slot_token, offs, h);
        k_ffn2_f32<<<dim3(DM/BN, ROWBLK), 256, 0, stream>>>(h, w2, b2, slot_token, slot_gate, offs, out);
    }
}

// Round 14
// 301.637 us; speedup vs baseline: 1.2795x; 1.1132x over previous
//
#include <hip/hip_runtime.h>
#include <stdint.h>

typedef unsigned short u16;
typedef __attribute__((ext_vector_type(8))) short s16x8;   // 8 bf16 (4 VGPRs)
typedef __attribute__((ext_vector_type(8))) u16  u16x8;
typedef __attribute__((ext_vector_type(4))) u16  u16x4;
typedef __attribute__((ext_vector_type(4))) float f32x4;

#define T_TOKENS 2048
#define DM 1024
#define DH 4096
#define NE 8
#define BK 64
#define BM 128
#define BN 128
#define MAXSLOTS (T_TOKENS*2 + NE*BM)   // 5120
#define ROWBLK (MAXSLOTS/BM)            // 40

__device__ __forceinline__ u16 f2bf(float f) {
    union { float ff; uint32_t u; } v; v.ff = f;
    uint32_t r = v.u + 0x7fffu + ((v.u >> 16) & 1u);   // RNE
    return (u16)(r >> 16);
}

// fast gelu (tanh form): max abs err ~3e-4 vs exact erf -> negligible after w2
__device__ __forceinline__ float gelu_fast(float v) {
    float u = v * (0.7978845608028654f + 0.03567740814183026f * v * v);
    u = fminf(fmaxf(u, -10.0f), 10.0f);
    float ex = __expf(2.0f * u);
    float th = 1.0f - 2.0f / (ex + 1.0f);
    return 0.5f * v * (1.0f + th);
}

#define GLOAD_LDS16(gsrc, ldst) \
    __builtin_amdgcn_global_load_lds((const __attribute__((address_space(1))) uint32_t*)(gsrc), \
                                     (__attribute__((address_space(3))) uint32_t*)(ldst), 16, 0, 0)

// counted waits: 8 loads per stage; next tile's 8 stay in flight while computing current
#define WAIT_VM8() asm volatile("s_waitcnt vmcnt(8)" ::: "memory")
#define WAIT_VM0() asm volatile("s_waitcnt vmcnt(0)" ::: "memory")

// ---------- K0b: windowed transpose + f32->bf16  dst[e][(n-nw0)][k] = src[e][k][n] ----------
__global__ void __launch_bounds__(256) k_transpose(const float* __restrict__ src,
                                                   u16* __restrict__ dst,
                                                   int K, int N, int nw0, int NW) {
    __shared__ float tile[64][65];
    const int e = blockIdx.z;
    const int n0 = nw0 + blockIdx.x * 64, k0 = blockIdx.y * 64;
    const float* s = src + (size_t)e * K * N;
    u16* d = dst + (size_t)e * K * NW;
    const int tx = threadIdx.x & 15, ty = threadIdx.x >> 4;
    #pragma unroll
    for (int j = 0; j < 4; ++j) {
        int r = ty * 4 + j;
        f32x4 v = *(const f32x4*)(s + (size_t)(k0 + r) * N + n0 + tx * 4);
        tile[r][tx*4+0] = v[0]; tile[r][tx*4+1] = v[1];
        tile[r][tx*4+2] = v[2]; tile[r][tx*4+3] = v[3];
    }
    __syncthreads();
    #pragma unroll
    for (int j = 0; j < 4; ++j) {
        int n = ty * 4 + j;
        u16x4 w;
        #pragma unroll
        for (int c = 0; c < 4; ++c) w[c] = f2bf(tile[tx*4+c][n]);
        *(u16x4*)(d + (size_t)(n0 - nw0 + n) * K + k0 + tx * 4) = w;
    }
}

// ---------- K1: gating (1 wave per token) + x f32->bf16 emit ----------
__global__ void __launch_bounds__(64) k_gate(const float* __restrict__ x,
                                             const float* __restrict__ gw,
                                             const float* __restrict__ gb,
                                             int* __restrict__ cnt,
                                             int* __restrict__ tt_idx,
                                             float* __restrict__ tt_w,
                                             u16* __restrict__ xbf) {
    const int t = blockIdx.x;
    const int lane = threadIdx.x;
    float acc[NE] = {0.f,0.f,0.f,0.f,0.f,0.f,0.f,0.f};
    const float* xr = x + (size_t)t * DM;
    u16* xbr = xbf + (size_t)t * DM;
    #pragma unroll
    for (int c = 0; c < DM/64; ++c) {
        float xv = xr[lane + 64*c];
        xbr[lane + 64*c] = f2bf(xv);                        // fused convert
        const float* g = gw + (size_t)(lane + 64*c) * NE;
        #pragma unroll
        for (int e = 0; e < NE; ++e) acc[e] += xv * g[e];
    }
    #pragma unroll
    for (int e = 0; e < NE; ++e) {
        #pragma unroll
        for (int off = 32; off >= 1; off >>= 1)
            acc[e] += __shfl_xor(acc[e], off, 64);
    }
    if (lane == 0) {
        float l[NE];
        #pragma unroll
        for (int e = 0; e < NE; ++e) l[e] = acc[e] + gb[e];
        int i0 = 0;
        #pragma unroll
        for (int e = 1; e < NE; ++e) if (l[e] > l[i0]) i0 = e;
        int i1 = (i0 == 0) ? 1 : 0;
        #pragma unroll
        for (int e = 0; e < NE; ++e) if (e != i0 && l[e] > l[i1]) i1 = e;
        float m  = l[i0];
        float w0 = expf(l[i0] - m), w1 = expf(l[i1] - m);
        float s = w0 + w1; w0 /= s; w1 /= s;
        tt_idx[t*2] = i0; tt_idx[t*2+1] = i1;
        tt_w[t*2] = w0;  tt_w[t*2+1] = w1;
        atomicAdd(&cnt[i0], 1); atomicAdd(&cnt[i1], 1);
    }
}

// ---------- K2: pad-aligned expert offsets ----------
__global__ void k_offsets(const int* __restrict__ cnt, int* __restrict__ fill,
                          int* __restrict__ off, int pad) {
    if (threadIdx.x == 0 && blockIdx.x == 0) {
        int a = 0;
        for (int e = 0; e < NE; ++e) {
            off[e] = a;
            a += (cnt[e] + pad - 1) / pad * pad;
            fill[e] = 0;
        }
        off[NE] = a;
    }
}

// ---------- K3: scatter token->slot ----------
__global__ void k_scatter(const int* __restrict__ tt_idx, const float* __restrict__ tt_w,
                          const int* __restrict__ off, int* __restrict__ fill,
                          int* __restrict__ slot_token, float* __restrict__ slot_gate) {
    int t = blockIdx.x * blockDim.x + threadIdx.x;
    if (t >= T_TOKENS) return;
    #pragma unroll
    for (int k = 0; k < 2; ++k) {
        int e = tt_idx[t*2+k];
        int pos = off[e] + atomicAdd(&fill[e], 1);
        slot_token[pos] = t;
        slot_gate[pos]  = tt_w[t*2+k];
    }
}

// ---------- MFMA inner step: 128x128, 4 waves, wave tile 64x64 ----------
__device__ __forceinline__ void mma64(const u16* As, const u16* Bs, int lane,
                                      int wr, int wc, f32x4 acc[4][4]) {
    #pragma unroll
    for (int ko = 0; ko < 2; ++ko) {
        s16x8 af[4], bfr[4];
        #pragma unroll
        for (int m = 0; m < 4; ++m) {
            int row = wr*64 + m*16 + (lane & 15);
            int sl = (ko*4 + (lane >> 4)) ^ (row & 7);
            af[m] = *(const s16x8*)&As[row*BK + sl*8];
        }
        #pragma unroll
        for (int n = 0; n < 4; ++n) {
            int col = wc*64 + n*16 + (lane & 15);
            int sl = (ko*4 + (lane >> 4)) ^ (col & 7);
            bfr[n] = *(const s16x8*)&Bs[col*BK + sl*8];
        }
        #pragma unroll
        for (int m = 0; m < 4; ++m)
            #pragma unroll
            for (int n = 0; n < 4; ++n)
                acc[m][n] = __builtin_amdgcn_mfma_f32_16x16x32_bf16(af[m], bfr[n], acc[m][n], 0, 0, 0);
    }
}

// ================== best-measured structure: 2-buffer, counted vmcnt(8), 2 barriers ==================

// ---------- K4: GEMM1 128x128  h = gelu(x[gather] @ w1t_e^T + b1_e)  [round-10 config, 117 us] ----------
__global__ void __launch_bounds__(256) k_ffn1_b16(
    const u16* __restrict__ xbf, const u16* __restrict__ wt,   // wt: [e][n-local][k=DM]
    const float* __restrict__ b1, const int* __restrict__ slot_token,
    const int* __restrict__ off, u16* __restrict__ h, int cb0, int NW)
{
    __shared__ u16 As[2][BM*BK];   // 32 KB
    __shared__ u16 Bs[2][BN*BK];   // 32 KB
    const int rb = blockIdx.y, cbl = blockIdx.x;
    const int total = off[NE];
    const int r0 = rb * BM;
    if (r0 >= total) return;
    int e = 0;
    while (e < NE-1 && off[e+1] <= r0) e++;
    const u16* Bsrc = wt + (size_t)e * DM * NW;
    const float* be = b1 + (size_t)e * DH;
    const int colbase = (cb0 + cbl) * BN;

    const int tid = threadIdx.x;
    const int lane = tid & 63, wid = tid >> 6;
    const int wr = wid >> 1, wc = wid & 1;

    const u16* gA[4]; const u16* gB[4];
    #pragma unroll
    for (int i = 0; i < 4; ++i) {
        int row = wid*32 + i*8 + (lane >> 3);
        int g = (lane & 7) ^ (row & 7);
        int tok = slot_token[r0 + row];
        gA[i] = xbf + (size_t)tok * DM + g*8;
        gB[i] = Bsrc + (size_t)(cbl*BN + row) * DM + g*8;
    }

    f32x4 acc[4][4];
    #pragma unroll
    for (int m = 0; m < 4; ++m)
        #pragma unroll
        for (int n = 0; n < 4; ++n) acc[m][n] = (f32x4){0.f,0.f,0.f,0.f};

    #define STG1(buf, kt) do {                                                \
        _Pragma("unroll")                                                     \
        for (int i = 0; i < 4; ++i) {                                         \
            GLOAD_LDS16(gA[i] + (kt)*BK, &As[buf][(wid*32 + i*8)*BK]);        \
            GLOAD_LDS16(gB[i] + (kt)*BK, &Bs[buf][(wid*32 + i*8)*BK]);        \
        }                                                                     \
    } while (0)

    const int NT = DM / BK;   // 16
    STG1(0, 0);
    STG1(1, 1);
    #pragma unroll 1
    for (int kt = 0; kt < NT; ++kt) {
        if (kt + 1 < NT) WAIT_VM8(); else WAIT_VM0();
        __builtin_amdgcn_s_barrier();
        __builtin_amdgcn_s_setprio(1);
        mma64(As[kt & 1], Bs[kt & 1], lane, wr, wc, acc);
        __builtin_amdgcn_s_setprio(0);
        __builtin_amdgcn_s_barrier();
        if (kt + 2 < NT) STG1(kt & 1, kt + 2);
    }
    #undef STG1

    #pragma unroll
    for (int n = 0; n < 4; ++n) {
        int col = colbase + wc*64 + n*16 + (lane & 15);
        float bb = be[col];
        #pragma unroll
        for (int m = 0; m < 4; ++m) {
            int rbase = r0 + wr*64 + m*16 + (lane >> 4)*4;
            #pragma unroll
            for (int i = 0; i < 4; ++i) {
                float v = acc[m][n][i] + bb;
                h[(size_t)(rbase + i)*DH + col] = f2bf(gelu_fast(v));
            }
        }
    }
}

// ---------- K5: GEMM2 128x128 non-split  out[tok] += gate * (h @ w2t_e^T + b2_e) [round-8 cfg] ----------
__global__ void __launch_bounds__(256) k_ffn2_b16(
    const u16* __restrict__ h, const u16* __restrict__ w2t,    // w2t: [e][n=DM][k=DH]
    const float* __restrict__ b2, const int* __restrict__ slot_token,
    const float* __restrict__ slot_gate, const int* __restrict__ off,
    float* __restrict__ out)
{
    __shared__ u16 As[2][BM*BK];
    __shared__ u16 Bs[2][BN*BK];
    const int rb = blockIdx.y, cb = blockIdx.x;
    const int total = off[NE];
    const int r0 = rb * BM;
    if (r0 >= total) return;
    int e = 0;
    while (e < NE-1 && off[e+1] <= r0) e++;
    const u16* Bsrc = w2t + (size_t)e * DH * DM;
    const float* be = b2 + (size_t)e * DM;

    const int tid = threadIdx.x;
    const int lane = tid & 63, wid = tid >> 6;
    const int wr = wid >> 1, wc = wid & 1;

    const u16* gA[4]; const u16* gB[4];
    #pragma unroll
    for (int i = 0; i < 4; ++i) {
        int row = wid*32 + i*8 + (lane >> 3);
        int g = (lane & 7) ^ (row & 7);
        gA[i] = h + (size_t)(r0 + row) * DH + g*8;
        gB[i] = Bsrc + (size_t)(cb*BN + row) * DH + g*8;
    }

    f32x4 acc[4][4];
    #pragma unroll
    for (int m = 0; m < 4; ++m)
        #pragma unroll
        for (int n = 0; n < 4; ++n) acc[m][n] = (f32x4){0.f,0.f,0.f,0.f};

    #define STG2(buf, kt) do {                                                \
        _Pragma("unroll")                                                     \
        for (int i = 0; i < 4; ++i) {                                         \
            GLOAD_LDS16(gA[i] + (kt)*BK, &As[buf][(wid*32 + i*8)*BK]);        \
            GLOAD_LDS16(gB[i] + (kt)*BK, &Bs[buf][(wid*32 + i*8)*BK]);        \
        }                                                                     \
    } while (0)

    const int NT = DH / BK;   // 64
    STG2(0, 0);
    STG2(1, 1);
    #pragma unroll 1
    for (int kt = 0; kt < NT; ++kt) {
        if (kt + 1 < NT) WAIT_VM8(); else WAIT_VM0();
        __builtin_amdgcn_s_barrier();
        __builtin_amdgcn_s_setprio(1);
        mma64(As[kt & 1], Bs[kt & 1], lane, wr, wc, acc);
        __builtin_amdgcn_s_setprio(0);
        __builtin_amdgcn_s_barrier();
        if (kt + 2 < NT) STG2(kt & 1, kt + 2);
    }
    #undef STG2

    float bb[4];
    #pragma unroll
    for (int n = 0; n < 4; ++n) bb[n] = be[cb*BN + wc*64 + n*16 + (lane & 15)];
    #pragma unroll
    for (int m = 0; m < 4; ++m) {
        #pragma unroll
        for (int i = 0; i < 4; ++i) {
            int s = r0 + wr*64 + m*16 + (lane >> 4)*4 + i;
            int tok = slot_token[s];
            float g = slot_gate[s];
            if (g != 0.0f) {
                float* orow = out + (size_t)tok * DM + cb*BN + wc*64;
                #pragma unroll
                for (int n = 0; n < 4; ++n)
                    atomicAdd(orow + n*16 + (lane & 15), g * (acc[m][n][i] + bb[n]));
            }
        }
    }
}

// ================== f32-weight fallback path ==================

__global__ void __launch_bounds__(256) k_ffn1_f32(
    const u16* __restrict__ xbf, const float* __restrict__ w1,
    const float* __restrict__ b1, const int* __restrict__ slot_token,
    const int* __restrict__ off, u16* __restrict__ h)
{
    __shared__ u16 As[BM*BK];
    __shared__ u16 Bs[BN*BK];
    const int rb = blockIdx.y, cb = blockIdx.x;
    const int total = off[NE];
    const int r0 = rb * BM;
    if (r0 >= total) return;
    int e = 0;
    while (e < NE-1 && off[e+1] <= r0) e++;
    const float* Bsrc = w1 + (size_t)e * DM * DH;
    const float* be   = b1 + (size_t)e * DH;

    const int tid = threadIdx.x;
    const int lane = tid & 63, wid = tid >> 6;
    const int wr = wid >> 1, wc = wid & 1;

    const u16* gA[4];
    #pragma unroll
    for (int i = 0; i < 4; ++i) {
        int row = wid*32 + i*8 + (lane >> 3);
        int g = (lane & 7) ^ (row & 7);
        int tok = slot_token[r0 + row];
        gA[i] = xbf + (size_t)tok * DM + g*8;
    }
    const int tc = tid & 31, tr = tid >> 5;
    const float* gB = Bsrc + (size_t)(tr*8) * DH + cb*BN + tc*4;

    f32x4 acc[4][4];
    #pragma unroll
    for (int m = 0; m < 4; ++m)
        #pragma unroll
        for (int n = 0; n < 4; ++n) acc[m][n] = (f32x4){0.f,0.f,0.f,0.f};

    for (int kt = 0; kt < DM/BK; ++kt) {
        #pragma unroll
        for (int i = 0; i < 4; ++i)
            GLOAD_LDS16(gA[i] + kt*BK, &As[(wid*32 + i*8)*BK]);
        f32x4 bv[8];
        #pragma unroll
        for (int j = 0; j < 8; ++j)
            bv[j] = *(const f32x4*)(gB + (size_t)(kt*BK + j) * DH);
        #pragma unroll
        for (int c = 0; c < 4; ++c) {
            int n = tc*4 + c;
            int sl = tr ^ (n & 7);
            s16x8 pk;
            #pragma unroll
            for (int j = 0; j < 8; ++j) pk[j] = (short)f2bf(bv[j][c]);
            *(s16x8*)&Bs[n*BK + sl*8] = pk;
        }
        __syncthreads();
        mma64(As, Bs, lane, wr, wc, acc);
        __syncthreads();
    }
    #pragma unroll
    for (int n = 0; n < 4; ++n) {
        int col = cb*BN + wc*64 + n*16 + (lane & 15);
        float bb = be[col];
        #pragma unroll
        for (int m = 0; m < 4; ++m) {
            int rbase = r0 + wr*64 + m*16 + (lane >> 4)*4;
            #pragma unroll
            for (int i = 0; i < 4; ++i) {
                float v = acc[m][n][i] + bb;
                h[(size_t)(rbase + i)*DH + col] = f2bf(gelu_fast(v));
            }
        }
    }
}

__global__ void __launch_bounds__(256) k_ffn2_f32(
    const u16* __restrict__ h, const float* __restrict__ w2,
    const float* __restrict__ b2, const int* __restrict__ slot_token,
    const float* __restrict__ slot_gate, const int* __restrict__ off,
    float* __restrict__ out)
{
    __shared__ u16 As[BM*BK];
    __shared__ u16 Bs[BN*BK];
    const int rb = blockIdx.y, cb = blockIdx.x;
    const int total = off[NE];
    const int r0 = rb * BM;
    if (r0 >= total) return;
    int e = 0;
    while (e < NE-1 && off[e+1] <= r0) e++;
    const float* Bsrc = w2 + (size_t)e * DH * DM;
    const float* be   = b2 + (size_t)e * DM;

    const int tid = threadIdx.x;
    const int lane = tid & 63, wid = tid >> 6;
    const int wr = wid >> 1, wc = wid & 1;

    const u16* gA[4];
    #pragma unroll
    for (int i = 0; i < 4; ++i) {
        int row = wid*32 + i*8 + (lane >> 3);
        int g = (lane & 7) ^ (row & 7);
        gA[i] = h + (size_t)(r0 + row) * DH + g*8;
    }
    const int tc = tid & 31, tr = tid >> 5;
    const float* gB = Bsrc + (size_t)(tr*8) * DM + cb*BN + tc*4;

    f32x4 acc[4][4];
    #pragma unroll
    for (int m = 0; m < 4; ++m)
        #pragma unroll
        for (int n = 0; n < 4; ++n) acc[m][n] = (f32x4){0.f,0.f,0.f,0.f};

    for (int kt = 0; kt < DH/BK; ++kt) {
        #pragma unroll
        for (int i = 0; i < 4; ++i)
            GLOAD_LDS16(gA[i] + kt*BK, &As[(wid*32 + i*8)*BK]);
        f32x4 bv[8];
        #pragma unroll
        for (int j = 0; j < 8; ++j)
            bv[j] = *(const f32x4*)(gB + (size_t)(kt*BK + j) * DM);
        #pragma unroll
        for (int c = 0; c < 4; ++c) {
            int n = tc*4 + c;
            int sl = tr ^ (n & 7);
            s16x8 pk;
            #pragma unroll
            for (int j = 0; j < 8; ++j) pk[j] = (short)f2bf(bv[j][c]);
            *(s16x8*)&Bs[n*BK + sl*8] = pk;
        }
        __syncthreads();
        mma64(As, Bs, lane, wr, wc, acc);
        __syncthreads();
    }
    float bb[4];
    #pragma unroll
    for (int n = 0; n < 4; ++n) bb[n] = be[cb*BN + wc*64 + n*16 + (lane & 15)];
    #pragma unroll
    for (int m = 0; m < 4; ++m) {
        #pragma unroll
        for (int i = 0; i < 4; ++i) {
            int s = r0 + wr*64 + m*16 + (lane >> 4)*4 + i;
            int tok = slot_token[s];
            float g = slot_gate[s];
            if (g != 0.0f) {
                float* orow = out + (size_t)tok * DM + cb*BN + wc*64;
                #pragma unroll
                for (int n = 0; n < 4; ++n)
                    atomicAdd(orow + n*16 + (lane & 15), g * (acc[m][n][i] + bb[n]));
            }
        }
    }
}

extern "C" void kernel_launch(void* const* d_in, const int* in_sizes, int n_in,
                              void* d_out, int out_size, void* d_ws, size_t ws_size,
                              hipStream_t stream)
{
    (void)in_sizes; (void)n_in; (void)out_size;
    const float* x  = (const float*)d_in[0];
    const float* gw = (const float*)d_in[1];
    const float* gb = (const float*)d_in[2];
    const float* w1 = (const float*)d_in[3];
    const float* b1 = (const float*)d_in[4];
    const float* w2 = (const float*)d_in[5];
    const float* b2 = (const float*)d_in[6];
    float* out = (float*)d_out;
    char* ws = (char*)d_ws;

    // layout: xbf 4MiB | h 40MiB (5120x4096 bf16) | ctrl arrays | wt (64 or 32 MiB)
    const size_t OFF_XBF = 0;
    const size_t OFF_H   = 4194304;
    const size_t OFF_ST  = OFF_H + (size_t)MAXSLOTS * DH * 2;  // 46137344
    const size_t OFF_SG  = OFF_ST + MAXSLOTS * 4;
    const size_t OFF_TI  = OFF_SG + MAXSLOTS * 4;
    const size_t OFF_TW  = OFF_TI + T_TOKENS * 2 * 4;
    const size_t OFF_CT  = OFF_TW + T_TOKENS * 2 * 4;
    const size_t OFF_WT  = (OFF_CT + 128 + 255) & ~(size_t)255;
    const size_t NEED_FULL = OFF_WT + (size_t)NE * DM * DH * 2;          // ~108.1 MiB
    const size_t NEED_HALF = OFF_WT + (size_t)NE * DM * (DH/2) * 2;      // ~76.1 MiB

    if (ws_size >= NEED_HALF) {
        u16*   xbf        = (u16*)(ws + OFF_XBF);
        u16*   h          = (u16*)(ws + OFF_H);
        int*   slot_token = (int*)(ws + OFF_ST);
        float* slot_gate  = (float*)(ws + OFF_SG);
        int*   tt_idx     = (int*)(ws + OFF_TI);
        float* tt_w       = (float*)(ws + OFF_TW);
        int*   ctrl       = (int*)(ws + OFF_CT);
        u16*   wt         = (u16*)(ws + OFF_WT);
        int* cnt = ctrl; int* fill = ctrl + 8; int* offs = ctrl + 16;
        const int full = (ws_size >= NEED_FULL);

        hipMemsetAsync(ctrl, 0, 128, stream);                       // cnt/fill/offs zero
        hipMemsetAsync(slot_token, 0, 2 * MAXSLOTS * 4, stream);    // tokens + gates (pads -> gate 0)
        hipMemsetAsync(out, 0, (size_t)T_TOKENS * DM * sizeof(float), stream);

        k_gate<<<T_TOKENS, 64, 0, stream>>>(x, gw, gb, cnt, tt_idx, tt_w, xbf);
        k_offsets<<<1, 64, 0, stream>>>(cnt, fill, offs, BM);
        k_scatter<<<(T_TOKENS + 255)/256, 256, 0, stream>>>(tt_idx, tt_w, offs, fill,
                                                            slot_token, slot_gate);

        if (full) {
            k_transpose<<<dim3(DH/64, DM/64, NE), 256, 0, stream>>>(w1, wt, DM, DH, 0, DH);
            k_ffn1_b16<<<dim3(DH/BN, ROWBLK), 256, 0, stream>>>(xbf, wt, b1, slot_token, offs, h, 0, DH);
        } else {
            k_transpose<<<dim3(DH/128, DM/64, NE), 256, 0, stream>>>(w1, wt, DM, DH, 0, DH/2);
            k_ffn1_b16<<<dim3(DH/256, ROWBLK), 256, 0, stream>>>(xbf, wt, b1, slot_token, offs, h, 0, DH/2);
            k_transpose<<<dim3(DH/128, DM/64, NE), 256, 0, stream>>>(w1, wt, DM, DH, DH/2, DH/2);
            k_ffn1_b16<<<dim3(DH/256, ROWBLK), 256, 0, stream>>>(xbf, wt, b1, slot_token, offs, h, DH/256, DH/2);
        }
        // w2t[e][n=DM][k=DH]
        k_transpose<<<dim3(DM/64, DH/64, NE), 256, 0, stream>>>(w2, wt, DH, DM, 0, DM);
        k_ffn2_b16<<<dim3(DM/BN, ROWBLK), 256, 0, stream>>>(h, wt, b2, slot_token, slot_gate, offs, out);
    } else {
        // f32-weight fallback
        u16*   xbf        = (u16*)(ws);
        u16*   h          = (u16*)(ws + OFF_H);
        int*   slot_token = (int*)(ws + OFF_ST);
        float* slot_gate  = (float*)(ws + OFF_SG);
        int*   tt_idx     = (int*)(ws + OFF_TI);
        float* tt_w       = (float*)(ws + OFF_TW);
        int*   ctrl       = (int*)(ws + OFF_CT);
        int* cnt = ctrl; int* fill = ctrl + 8; int* offs = ctrl + 16;

        hipMemsetAsync(ctrl, 0, 128, stream);
        hipMemsetAsync(slot_token, 0, 2 * MAXSLOTS * 4, stream);
        hipMemsetAsync(out, 0, (size_t)T_TOKENS * DM * sizeof(float), stream);

        k_gate<<<T_TOKENS, 64, 0, stream>>>(x, gw, gb, cnt, tt_idx, tt_w, xbf);
        k_offsets<<<1, 64, 0, stream>>>(cnt, fill, offs, BM);
        k_scatter<<<(T_TOKENS + 255)/256, 256, 0, stream>>>(tt_idx, tt_w, offs, fill,
                                                            slot_token, slot_gate);
        k_ffn1_f32<<<dim3(DH/BN, ROWBLK), 256, 0, stream>>>(xbf, w1, b1, slot_token, offs, h);
        k_ffn2_f32<<<dim3(DM/BN, ROWBLK), 256, 0, stream>>>(h, w2, b2, slot_token, slot_gate, offs, out);
    }
}